// Round 8
// baseline (181.640 us; speedup 1.0000x reference)
//
#include <hip/hip_runtime.h>
#include <hip/hip_bf16.h>

// GCN 2-layer: h1 = relu(GCNConv(x, W1, b1)); out = log_softmax(GCNConv(h1, W2, b2))
// GCNConv(h)[d] = dinv[d] * ( sum_{s->d} (h@W)[s]*dinv[s] + (h@W)[d]*dinv[d] ) + b
//
// Round-18: r17 (int4 edge reads, PART_G=512, parallel scan_bsum) gave
// 184.6 -> 180.9. This round continues preprocessing shaves, zero structural
// risk:
//  - all block scans (k_scan1, scan_bsum, bucket_csr's 256-scan) switch from
//    16-barrier Hillis-Steele to wave64 __shfl_up scan + 1 barrier
//  - k_bucket_csr stages its bucket's part slice (<=8192 edges, 32KB LDS)
//    once, fusing the degree count into the staging pass; the col-fill pass
//    reads LDS instead of a second 6.4MB global part pass (fallback to the
//    old 2-pass global path if a bucket ever exceeds 8192 edges)
// Gather/GEMM kernels unchanged from r16/r17.

#define FEAT_IN 64
#define FEAT_H  32
#define FEAT_O  16
#define MAXNB   512   // max buckets of 256 nodes (n <= 131072; n < 2^24 for packing)
#define PART_G  512   // histogram/partition blocks
#define MAXSNB  256   // max scan blocks for hlen = MAXNB*PART_G/1024
#define SPART   8192  // LDS-staged edges per bucket (mean 4096, sigma ~64)

__device__ __forceinline__ float2 upk_bf2(unsigned w) {
    return make_float2(__uint_as_float(w << 16), __uint_as_float(w & 0xFFFF0000u));
}

// wave64 inclusive scan of x (within-wave), no barriers
__device__ __forceinline__ int wave_incl_scan(int x, int lane) {
#pragma unroll
    for (int off = 1; off < 64; off <<= 1) {
        int y = __shfl_up(x, off);
        if (lane >= off) x += y;
    }
    return x;
}

// ---- pass 1: per-block bucket histogram -> hist[b*G + g] ----
__global__ void k_hist(const int* __restrict__ dst, int e,
                       int* __restrict__ hist, int G, int NBk) {
    __shared__ int lh[MAXNB];
    int t = threadIdx.x, g = blockIdx.x;
    for (int i = t; i < NBk; i += 256) lh[i] = 0;
    __syncthreads();
    int chunk = (((e + G - 1) / G) + 3) & ~3;   // 4-aligned chunks
    int beg = g * chunk, end = min(e, beg + chunk);
    if ((e & 3) == 0) {
        int vend = beg + ((end - beg) & ~3);
        for (int j = beg + 4 * t; j + 3 < vend; j += 1024) {
            int4 d = *(const int4*)&dst[j];
            atomicAdd(&lh[d.x >> 8], 1);
            atomicAdd(&lh[d.y >> 8], 1);
            atomicAdd(&lh[d.z >> 8], 1);
            atomicAdd(&lh[d.w >> 8], 1);
        }
        for (int j = vend + t; j < end; j += 256) atomicAdd(&lh[dst[j] >> 8], 1);
    } else {
        for (int i = beg + t; i < end; i += 256) atomicAdd(&lh[dst[i] >> 8], 1);
    }
    __syncthreads();
    for (int i = t; i < NBk; i += 256) hist[(size_t)i * G + g] = lh[i];
}

// ---- block-local exclusive scan (1024 items/block); bsum[b] = raw block sum ----
__global__ void k_scan1(const int* __restrict__ in, int* __restrict__ out,
                        int* __restrict__ bsum, int len) {
    __shared__ int wsum[4];
    int t = threadIdx.x;
    int base = blockIdx.x * 1024 + t * 4;
    int a0 = (base + 0) < len ? in[base + 0] : 0;
    int a1 = (base + 1) < len ? in[base + 1] : 0;
    int a2 = (base + 2) < len ? in[base + 2] : 0;
    int a3 = (base + 3) < len ? in[base + 3] : 0;
    int tsum = a0 + a1 + a2 + a3;
    int lane = t & 63, wid = t >> 6;
    int x = wave_incl_scan(tsum, lane);
    if (lane == 63) wsum[wid] = x;
    __syncthreads();
    int woff = 0;
#pragma unroll
    for (int w = 0; w < 4; ++w) woff += (w < wid) ? wsum[w] : 0;
    int ex = x + woff - tsum;
    if (base + 0 < len) out[base + 0] = ex;
    if (base + 1 < len) out[base + 1] = ex + a0;
    if (base + 2 < len) out[base + 2] = ex + a0 + a1;
    if (base + 3 < len) out[base + 3] = ex + a0 + a1 + a2;
    if (t == 255) bsum[blockIdx.x] = x + woff;   // block total
}

// helper: exclusive scan of raw bsum[snb] into sps[256]; 1 barrier inside
__device__ __forceinline__ void scan_bsum(const int* __restrict__ bsum, int snb,
                                          int* __restrict__ sps, int t) {
    __shared__ int wsb[4];
    int v = (t < snb) ? bsum[t] : 0;
    int lane = t & 63, wid = t >> 6;
    int x = wave_incl_scan(v, lane);
    if (lane == 63) wsb[wid] = x;
    __syncthreads();
    int woff = 0;
#pragma unroll
    for (int w = 0; w < 4; ++w) woff += (w < wid) ? wsb[w] : 0;
    sps[t] = x + woff - v;   // exclusive prefix
    __syncthreads();
}

// ---- pass 2: scatter packed (src | dlow<<24) into bucket-ordered part[] ----
__global__ void k_partition(const int* __restrict__ src, const int* __restrict__ dst, int e,
                            const int* __restrict__ base, const int* __restrict__ bsum,
                            int snb, int* __restrict__ part, int G, int NBk) {
    __shared__ int cur[MAXNB];
    __shared__ int sps[MAXSNB];
    int t = threadIdx.x, g = blockIdx.x;
    scan_bsum(bsum, snb, sps, t);
    for (int i = t; i < NBk; i += 256) {
        size_t idx = (size_t)i * G + g;
        cur[i] = base[idx] + sps[idx >> 10];
    }
    __syncthreads();
    int chunk = (((e + G - 1) / G) + 3) & ~3;
    int beg = g * chunk, end = min(e, beg + chunk);
    if ((e & 3) == 0) {
        int vend = beg + ((end - beg) & ~3);
        for (int j = beg + 4 * t; j + 3 < vend; j += 1024) {
            int4 s4 = *(const int4*)&src[j];
            int4 d4 = *(const int4*)&dst[j];
            int p0 = atomicAdd(&cur[d4.x >> 8], 1); part[p0] = s4.x | ((d4.x & 255) << 24);
            int p1 = atomicAdd(&cur[d4.y >> 8], 1); part[p1] = s4.y | ((d4.y & 255) << 24);
            int p2 = atomicAdd(&cur[d4.z >> 8], 1); part[p2] = s4.z | ((d4.z & 255) << 24);
            int p3 = atomicAdd(&cur[d4.w >> 8], 1); part[p3] = s4.w | ((d4.w & 255) << 24);
        }
        for (int j = vend + t; j < end; j += 256) {
            int s_ = src[j], d_ = dst[j];
            int pos = atomicAdd(&cur[d_ >> 8], 1);
            part[pos] = s_ | ((d_ & 255) << 24);
        }
    } else {
        for (int i = beg + t; i < end; i += 256) {
            int s_ = src[i], d_ = dst[i];
            int pos = atomicAdd(&cur[d_ >> 8], 1);
            part[pos] = s_ | ((d_ & 255) << 24);
        }
    }
}

// ---- pass 3: per-bucket CSR: stage part slice in LDS (count fused) ->
//      shfl scan -> row_start/dinv -> col fill from LDS ----
__global__ void k_bucket_csr(const int* __restrict__ part, const int* __restrict__ base,
                             const int* __restrict__ bsum, int snb, int e, int G, int NBk,
                             int n, int* __restrict__ row_start, int* __restrict__ col,
                             float* __restrict__ dinv) {
    __shared__ int cnt[256], spre[256], cur[256];
    __shared__ int sps[MAXSNB];
    __shared__ int wsc[4];
    __shared__ int spart[SPART];
    int t = threadIdx.x, b = blockIdx.x;
    scan_bsum(bsum, snb, sps, t);
    size_t ib = (size_t)b * G;
    size_t ie = (size_t)(b + 1) * G;
    int beg = base[ib] + sps[ib >> 10];
    int end = (b == NBk - 1) ? e : (base[ie] + sps[ie >> 10]);
    int m = end - beg;
    cnt[t] = 0; cur[t] = 0;
    __syncthreads();
    bool fits = (m <= SPART);
    if (fits) {   // stage + count in one global pass
        for (int j = t; j < m; j += 256) {
            int r = part[beg + j];
            spart[j] = r;
            atomicAdd(&cnt[((unsigned)r) >> 24], 1);
        }
    } else {      // fallback: count from global
        for (int j = t; j < m; j += 256)
            atomicAdd(&cnt[((unsigned)part[beg + j]) >> 24], 1);
    }
    __syncthreads();
    int v = cnt[t];
    int lane = t & 63, wid = t >> 6;
    int x = wave_incl_scan(v, lane);
    if (lane == 63) wsc[wid] = x;
    __syncthreads();
    int woff = 0;
#pragma unroll
    for (int w = 0; w < 4; ++w) woff += (w < wid) ? wsc[w] : 0;
    int pre = x + woff - v;      // exclusive prefix within bucket
    spre[t] = pre;
    int node = b * 256 + t;
    if (node < n) {
        row_start[node] = beg + pre;
        dinv[node] = rsqrtf((float)v + 1.0f);  // +1 self-loop
    }
    if (b == NBk - 1 && t == 0) row_start[n] = e;
    __syncthreads();
    if (fits) {   // fill from LDS
        for (int j = t; j < m; j += 256) {
            int r = spart[j];
            int dl = ((unsigned)r) >> 24;
            int off = atomicAdd(&cur[dl], 1);
            col[beg + spre[dl] + off] = r & 0x00FFFFFF;
        }
    } else {      // fallback: fill from global
        for (int j = t; j < m; j += 256) {
            int r = part[beg + j];
            int dl = ((unsigned)r) >> 24;
            int off = atomicAdd(&cur[dl], 1);
            col[beg + spre[dl] + off] = r & 0x00FFFFFF;
        }
    }
}

// ---- layer 1 GEMM: h1s(bf16) = (x @ W1) * dinv ; 32 nodes/block ----
__global__ void k_gemm1(const float* __restrict__ x, const float* __restrict__ W1,
                        const float* __restrict__ dinv,
                        __hip_bfloat162* __restrict__ h1s2, int n) {
    __shared__ float sW[FEAT_IN * FEAT_H];   // 8 KB
    __shared__ float sx[16][FEAT_IN + 1];
    int t = threadIdx.x;
    for (int i = t; i < FEAT_IN * FEAT_H; i += 256) sW[i] = W1[i];
#pragma unroll
    for (int tile = 0; tile < 2; ++tile) {
        int nodeBase = blockIdx.x * 32 + tile * 16;
        __syncthreads();
        {   // stage 16 nodes of x
            int xn = t >> 4, c = t & 15;
            int node = nodeBase + xn;
            if (node < n) {
                float4 v = ((const float4*)x)[(size_t)node * 16 + c];
                sx[xn][c * 4 + 0] = v.x; sx[xn][c * 4 + 1] = v.y;
                sx[xn][c * 4 + 2] = v.z; sx[xn][c * 4 + 3] = v.w;
            }
        }
        __syncthreads();
        int nl = t >> 4, g = t & 15;
        int node = nodeBase + nl;
        if (node < n) {
            float a0 = 0.0f, a1 = 0.0f;
#pragma unroll
            for (int k = 0; k < FEAT_IN; ++k) {
                float s = sx[nl][k];
                a0 += s * sW[k * FEAT_H + 2 * g];
                a1 += s * sW[k * FEAT_H + 2 * g + 1];
            }
            float dv = dinv[node];
            __hip_bfloat162 o;
            o.x = __float2bfloat16(a0 * dv);
            o.y = __float2bfloat16(a1 * dv);
            h1s2[(size_t)node * 16 + g] = o;
        }
    }
}

#define ACC8(u) do { float2 p_;                         \
    p_ = upk_bf2((u).x); a[0] += p_.x; a[1] += p_.y;    \
    p_ = upk_bf2((u).y); a[2] += p_.x; a[3] += p_.y;    \
    p_ = upk_bf2((u).z); a[4] += p_.x; a[5] += p_.y;    \
    p_ = upk_bf2((u).w); a[6] += p_.x; a[7] += p_.y; } while (0)

// ---- gather layer1 (+relu+bias) fused with GEMM2: 64 nodes x 4 lanes ----
__global__ void k_gather1_gemm2(const int* __restrict__ row_start, const int* __restrict__ col,
                                const uint4* __restrict__ h1q, const float* __restrict__ W2,
                                const float* __restrict__ b1,
                                const float* __restrict__ dinv,
                                __hip_bfloat162* __restrict__ h2s2, int n) {
    __shared__ float sW[FEAT_H * FEAT_O];
    __shared__ float sb1[FEAT_H];
    __shared__ float sz[64][FEAT_H + 1];
    int t = threadIdx.x;
    for (int i = t; i < FEAT_H * FEAT_O; i += 256) sW[i] = W2[i];
    if (t < FEAT_H) sb1[t] = b1[t];
    __syncthreads();

    int g = t >> 2, l = t & 3;          // 64 nodes, 4 lanes each (16B bf16 = 8 feats)
    int d = blockIdx.x * 64 + g;
    if (d < n) {
        float a[8];
        {   // self-loop term
            uint4 u = h1q[(size_t)d * 4 + l];
            float2 p;
            p = upk_bf2(u.x); a[0] = p.x; a[1] = p.y;
            p = upk_bf2(u.y); a[2] = p.x; a[3] = p.y;
            p = upk_bf2(u.z); a[4] = p.x; a[5] = p.y;
            p = upk_bf2(u.w); a[6] = p.x; a[7] = p.y;
        }
        int beg = row_start[d], end = row_start[d + 1];
        int j = beg;
        for (; j + 8 <= end; j += 8) {   // 8 independent 16B gathers in flight
            int c0 = col[j + 0], c1 = col[j + 1], c2 = col[j + 2], c3 = col[j + 3];
            int c4 = col[j + 4], c5 = col[j + 5], c6 = col[j + 6], c7 = col[j + 7];
            uint4 u0 = h1q[(size_t)c0 * 4 + l];
            uint4 u1 = h1q[(size_t)c1 * 4 + l];
            uint4 u2 = h1q[(size_t)c2 * 4 + l];
            uint4 u3 = h1q[(size_t)c3 * 4 + l];
            uint4 u4 = h1q[(size_t)c4 * 4 + l];
            uint4 u5 = h1q[(size_t)c5 * 4 + l];
            uint4 u6 = h1q[(size_t)c6 * 4 + l];
            uint4 u7 = h1q[(size_t)c7 * 4 + l];
            ACC8(u0); ACC8(u1); ACC8(u2); ACC8(u3);
            ACC8(u4); ACC8(u5); ACC8(u6); ACC8(u7);
        }
        for (; j + 4 <= end; j += 4) {
            int c0 = col[j + 0], c1 = col[j + 1], c2 = col[j + 2], c3 = col[j + 3];
            uint4 u0 = h1q[(size_t)c0 * 4 + l];
            uint4 u1 = h1q[(size_t)c1 * 4 + l];
            uint4 u2 = h1q[(size_t)c2 * 4 + l];
            uint4 u3 = h1q[(size_t)c3 * 4 + l];
            ACC8(u0); ACC8(u1); ACC8(u2); ACC8(u3);
        }
        for (; j < end; ++j) {
            uint4 u = h1q[(size_t)col[j] * 4 + l];
            ACC8(u);
        }
        float dv = dinv[d];
#pragma unroll
        for (int k = 0; k < 8; ++k)
            sz[g][l * 8 + k] = fmaxf(dv * a[k] + sb1[l * 8 + k], 0.0f);
    }
    __syncthreads();
    // GEMM2: 64 nodes x 8 output-pairs = 512 items / 256 thr = 2 iters; bf16 store
#pragma unroll
    for (int it = 0; it < 2; ++it) {
        int nl = (t >> 3) + it * 32;
        int m = t & 7;
        int node = blockIdx.x * 64 + nl;
        if (node < n) {
            float a0 = 0.0f, a1 = 0.0f;
#pragma unroll
            for (int f = 0; f < FEAT_H; ++f) {
                float z = sz[nl][f];
                a0 += z * sW[f * FEAT_O + 2 * m];
                a1 += z * sW[f * FEAT_O + 2 * m + 1];
            }
            float dv = dinv[node];
            __hip_bfloat162 o;
            o.x = __float2bfloat16(a0 * dv);
            o.y = __float2bfloat16(a1 * dv);
            h2s2[(size_t)node * 8 + m] = o;
        }
    }
}

// ---- gather layer2 + bias + log_softmax: 128 nodes x 2 lanes ----
__global__ void k_gather2_lsm(const int* __restrict__ row_start, const int* __restrict__ col,
                              const uint4* __restrict__ h2q, const float* __restrict__ b2,
                              const float* __restrict__ dinv,
                              float4* __restrict__ out4, int n) {
    __shared__ float sb2[FEAT_O];
    int t = threadIdx.x;
    if (t < FEAT_O) sb2[t] = b2[t];
    __syncthreads();
    int g = t >> 1, h = t & 1;          // 128 nodes, 2 lanes each (16B bf16 = 8 feats)
    int d = blockIdx.x * 128 + g;
    if (d >= n) return;
    float a[8];
    {
        uint4 u = h2q[(size_t)d * 2 + h];  // self-loop term
        float2 p;
        p = upk_bf2(u.x); a[0] = p.x; a[1] = p.y;
        p = upk_bf2(u.y); a[2] = p.x; a[3] = p.y;
        p = upk_bf2(u.z); a[4] = p.x; a[5] = p.y;
        p = upk_bf2(u.w); a[6] = p.x; a[7] = p.y;
    }
    int beg = row_start[d], end = row_start[d + 1];
    int j = beg;
    for (; j + 8 <= end; j += 8) {   // 8 independent 16B gathers in flight
        int c0 = col[j + 0], c1 = col[j + 1], c2 = col[j + 2], c3 = col[j + 3];
        int c4 = col[j + 4], c5 = col[j + 5], c6 = col[j + 6], c7 = col[j + 7];
        uint4 u0 = h2q[(size_t)c0 * 2 + h];
        uint4 u1 = h2q[(size_t)c1 * 2 + h];
        uint4 u2 = h2q[(size_t)c2 * 2 + h];
        uint4 u3 = h2q[(size_t)c3 * 2 + h];
        uint4 u4 = h2q[(size_t)c4 * 2 + h];
        uint4 u5 = h2q[(size_t)c5 * 2 + h];
        uint4 u6 = h2q[(size_t)c6 * 2 + h];
        uint4 u7 = h2q[(size_t)c7 * 2 + h];
        ACC8(u0); ACC8(u1); ACC8(u2); ACC8(u3);
        ACC8(u4); ACC8(u5); ACC8(u6); ACC8(u7);
    }
    for (; j + 4 <= end; j += 4) {
        int c0 = col[j + 0], c1 = col[j + 1], c2 = col[j + 2], c3 = col[j + 3];
        uint4 u0 = h2q[(size_t)c0 * 2 + h];
        uint4 u1 = h2q[(size_t)c1 * 2 + h];
        uint4 u2 = h2q[(size_t)c2 * 2 + h];
        uint4 u3 = h2q[(size_t)c3 * 2 + h];
        ACC8(u0); ACC8(u1); ACC8(u2); ACC8(u3);
    }
    for (; j < end; ++j) {
        uint4 u = h2q[(size_t)col[j] * 2 + h];
        ACC8(u);
    }
    float dv = dinv[d];
    float v[8];
    float mx = -1e30f;
#pragma unroll
    for (int k = 0; k < 8; ++k) {
        v[k] = dv * a[k] + sb2[h * 8 + k];
        mx = fmaxf(mx, v[k]);
    }
    mx = fmaxf(mx, __shfl_xor(mx, 1));   // partner lane = same node, other half
    float ssum = 0.0f;
#pragma unroll
    for (int k = 0; k < 8; ++k) ssum += __expf(v[k] - mx);
    ssum += __shfl_xor(ssum, 1);
    float lg = mx + logf(ssum);
    float4 o0 = { v[0] - lg, v[1] - lg, v[2] - lg, v[3] - lg };
    float4 o1 = { v[4] - lg, v[5] - lg, v[6] - lg, v[7] - lg };
    out4[(size_t)d * 4 + h * 2 + 0] = o0;
    out4[(size_t)d * 4 + h * 2 + 1] = o1;
}

extern "C" void kernel_launch(void* const* d_in, const int* in_sizes, int n_in,
                              void* d_out, int out_size, void* d_ws, size_t ws_size,
                              hipStream_t stream) {
    const float* x  = (const float*)d_in[0];
    const int*   ei = (const int*)d_in[1];
    const float* W1 = (const float*)d_in[2];
    const float* b1 = (const float*)d_in[3];
    const float* W2 = (const float*)d_in[4];
    const float* b2 = (const float*)d_in[5];

    const int n = in_sizes[0] / FEAT_IN;   // 100000
    const int e = in_sizes[1] / 2;         // 1600000
    const int* src = ei;
    const int* dst = ei + e;
    const int NBk = (n + 255) >> 8;        // 391 buckets of 256
    const int G = PART_G;                  // 512
    const int hlen = NBk * G;              // 200192
    const int snb = (hlen + 1023) / 1024;  // 196 (<= MAXSNB)

    // workspace; part (4B*e = 6.4MB) aliased with h1s bf16 (32n*2B = 6.4MB):
    // bucket_csr fully consumes part before k_gemm1 writes h1s (stream-ordered)
    int* part = (int*)d_ws;                                   // e ints
    __hip_bfloat162* h1s2 = (__hip_bfloat162*)d_ws;           // 16n bf162, same region
    int* col  = (int*)d_ws + e;                               // e ints
    __hip_bfloat162* h2s2 = (__hip_bfloat162*)(col + e);      // 8n bf162 (3.2MB)
    float* dinv = (float*)(h2s2 + 8 * (size_t)n);             // n
    int* hist      = (int*)(dinv + n);                        // hlen
    int* base      = hist + hlen;                             // hlen
    int* bsum      = base + hlen;                             // snb (raw block sums)
    int* row_start = bsum + MAXSNB;                           // n+1

    k_hist<<<G, 256, 0, stream>>>(dst, e, hist, G, NBk);
    k_scan1<<<snb, 256, 0, stream>>>(hist, base, bsum, hlen);
    k_partition<<<G, 256, 0, stream>>>(src, dst, e, base, bsum, snb, part, G, NBk);
    k_bucket_csr<<<NBk, 256, 0, stream>>>(part, base, bsum, snb, e, G, NBk, n,
                                          row_start, col, dinv);

    k_gemm1<<<(n + 31) / 32, 256, 0, stream>>>(x, W1, dinv, h1s2, n);
    k_gather1_gemm2<<<(n + 63) / 64, 256, 0, stream>>>(row_start, col, (const uint4*)h1s2,
                                                       W2, b1, dinv, h2s2, n);
    k_gather2_lsm<<<(n + 127) / 128, 256, 0, stream>>>(row_start, col, (const uint4*)h2s2,
                                                       b2, dinv, (float4*)d_out, n);
}

// Round 9
// 179.309 us; speedup vs baseline: 1.0130x; 1.0130x over previous
//
#include <hip/hip_runtime.h>
#include <hip/hip_bf16.h>

// GCN 2-layer: h1 = relu(GCNConv(x, W1, b1)); out = log_softmax(GCNConv(h1, W2, b2))
// GCNConv(h)[d] = dinv[d] * ( sum_{s->d} (h@W)[s]*dinv[s] + (h@W)[d]*dinv[d] ) + b
//
// Round-19: r6 (unroll-8) neutral => gather MLP slot-saturated; r7/r8 =>
// preprocessing at floor. Remaining lever: gather SERVICE LATENCY. h1s
// (6.4MB) exceeds 4MB per-XCD L2 -> random reads mix L2 and LLC latency.
// This round: order each row's neighbors by src QUARTILE during the
// bucket_csr fill (per-(node,quartile) LDS cursors). Gather kernels are
// byte-for-byte unchanged; their row loops now touch low node-ids early and
// high node-ids late, shrinking the instantaneous working set to ~1.6MB
// (L2-resident) per soft phase. Row-internal edge order is semantically free
// (was already atomic-nondeterministic).

#define FEAT_IN 64
#define FEAT_H  32
#define FEAT_O  16
#define MAXNB   512   // max buckets of 256 nodes (n <= 131072; n < 2^24 for packing)
#define PART_G  512   // histogram/partition blocks
#define MAXSNB  256   // max scan blocks for hlen = MAXNB*PART_G/1024
#define SPART   8192  // LDS-staged edges per bucket (mean 4096, sigma ~64)

__device__ __forceinline__ float2 upk_bf2(unsigned w) {
    return make_float2(__uint_as_float(w << 16), __uint_as_float(w & 0xFFFF0000u));
}

// wave64 inclusive scan of x (within-wave), no barriers
__device__ __forceinline__ int wave_incl_scan(int x, int lane) {
#pragma unroll
    for (int off = 1; off < 64; off <<= 1) {
        int y = __shfl_up(x, off);
        if (lane >= off) x += y;
    }
    return x;
}

// ---- pass 1: per-block bucket histogram -> hist[b*G + g] ----
__global__ void k_hist(const int* __restrict__ dst, int e,
                       int* __restrict__ hist, int G, int NBk) {
    __shared__ int lh[MAXNB];
    int t = threadIdx.x, g = blockIdx.x;
    for (int i = t; i < NBk; i += 256) lh[i] = 0;
    __syncthreads();
    int chunk = (((e + G - 1) / G) + 3) & ~3;   // 4-aligned chunks
    int beg = g * chunk, end = min(e, beg + chunk);
    if ((e & 3) == 0) {
        int vend = beg + ((end - beg) & ~3);
        for (int j = beg + 4 * t; j + 3 < vend; j += 1024) {
            int4 d = *(const int4*)&dst[j];
            atomicAdd(&lh[d.x >> 8], 1);
            atomicAdd(&lh[d.y >> 8], 1);
            atomicAdd(&lh[d.z >> 8], 1);
            atomicAdd(&lh[d.w >> 8], 1);
        }
        for (int j = vend + t; j < end; j += 256) atomicAdd(&lh[dst[j] >> 8], 1);
    } else {
        for (int i = beg + t; i < end; i += 256) atomicAdd(&lh[dst[i] >> 8], 1);
    }
    __syncthreads();
    for (int i = t; i < NBk; i += 256) hist[(size_t)i * G + g] = lh[i];
}

// ---- block-local exclusive scan (1024 items/block); bsum[b] = raw block sum ----
__global__ void k_scan1(const int* __restrict__ in, int* __restrict__ out,
                        int* __restrict__ bsum, int len) {
    __shared__ int wsum[4];
    int t = threadIdx.x;
    int base = blockIdx.x * 1024 + t * 4;
    int a0 = (base + 0) < len ? in[base + 0] : 0;
    int a1 = (base + 1) < len ? in[base + 1] : 0;
    int a2 = (base + 2) < len ? in[base + 2] : 0;
    int a3 = (base + 3) < len ? in[base + 3] : 0;
    int tsum = a0 + a1 + a2 + a3;
    int lane = t & 63, wid = t >> 6;
    int x = wave_incl_scan(tsum, lane);
    if (lane == 63) wsum[wid] = x;
    __syncthreads();
    int woff = 0;
#pragma unroll
    for (int w = 0; w < 4; ++w) woff += (w < wid) ? wsum[w] : 0;
    int ex = x + woff - tsum;
    if (base + 0 < len) out[base + 0] = ex;
    if (base + 1 < len) out[base + 1] = ex + a0;
    if (base + 2 < len) out[base + 2] = ex + a0 + a1;
    if (base + 3 < len) out[base + 3] = ex + a0 + a1 + a2;
    if (t == 255) bsum[blockIdx.x] = x + woff;   // block total
}

// helper: exclusive scan of raw bsum[snb] into sps[256]; 1 barrier inside
__device__ __forceinline__ void scan_bsum(const int* __restrict__ bsum, int snb,
                                          int* __restrict__ sps, int t) {
    __shared__ int wsb[4];
    int v = (t < snb) ? bsum[t] : 0;
    int lane = t & 63, wid = t >> 6;
    int x = wave_incl_scan(v, lane);
    if (lane == 63) wsb[wid] = x;
    __syncthreads();
    int woff = 0;
#pragma unroll
    for (int w = 0; w < 4; ++w) woff += (w < wid) ? wsb[w] : 0;
    sps[t] = x + woff - v;   // exclusive prefix
    __syncthreads();
}

// ---- pass 2: scatter packed (src | dlow<<24) into bucket-ordered part[] ----
__global__ void k_partition(const int* __restrict__ src, const int* __restrict__ dst, int e,
                            const int* __restrict__ base, const int* __restrict__ bsum,
                            int snb, int* __restrict__ part, int G, int NBk) {
    __shared__ int cur[MAXNB];
    __shared__ int sps[MAXSNB];
    int t = threadIdx.x, g = blockIdx.x;
    scan_bsum(bsum, snb, sps, t);
    for (int i = t; i < NBk; i += 256) {
        size_t idx = (size_t)i * G + g;
        cur[i] = base[idx] + sps[idx >> 10];
    }
    __syncthreads();
    int chunk = (((e + G - 1) / G) + 3) & ~3;
    int beg = g * chunk, end = min(e, beg + chunk);
    if ((e & 3) == 0) {
        int vend = beg + ((end - beg) & ~3);
        for (int j = beg + 4 * t; j + 3 < vend; j += 1024) {
            int4 s4 = *(const int4*)&src[j];
            int4 d4 = *(const int4*)&dst[j];
            int p0 = atomicAdd(&cur[d4.x >> 8], 1); part[p0] = s4.x | ((d4.x & 255) << 24);
            int p1 = atomicAdd(&cur[d4.y >> 8], 1); part[p1] = s4.y | ((d4.y & 255) << 24);
            int p2 = atomicAdd(&cur[d4.z >> 8], 1); part[p2] = s4.z | ((d4.z & 255) << 24);
            int p3 = atomicAdd(&cur[d4.w >> 8], 1); part[p3] = s4.w | ((d4.w & 255) << 24);
        }
        for (int j = vend + t; j < end; j += 256) {
            int s_ = src[j], d_ = dst[j];
            int pos = atomicAdd(&cur[d_ >> 8], 1);
            part[pos] = s_ | ((d_ & 255) << 24);
        }
    } else {
        for (int i = beg + t; i < end; i += 256) {
            int s_ = src[i], d_ = dst[i];
            int pos = atomicAdd(&cur[d_ >> 8], 1);
            part[pos] = s_ | ((d_ & 255) << 24);
        }
    }
}

// ---- pass 3: per-bucket CSR with per-row src-QUARTILE ordering ----
__global__ void k_bucket_csr(const int* __restrict__ part, const int* __restrict__ base,
                             const int* __restrict__ bsum, int snb, int e, int G, int NBk,
                             int n, int* __restrict__ row_start, int* __restrict__ col,
                             float* __restrict__ dinv) {
    __shared__ int cntq[256][4];   // per-(node,quartile) counts -> qpre
    __shared__ int curq[256][4];   // per-(node,quartile) fill cursors
    __shared__ int spre[256];
    __shared__ int sps[MAXSNB];
    __shared__ int wsc[4];
    __shared__ int spart[SPART];
    int t = threadIdx.x, b = blockIdx.x;
    scan_bsum(bsum, snb, sps, t);
    size_t ib = (size_t)b * G;
    size_t ie = (size_t)(b + 1) * G;
    int beg = base[ib] + sps[ib >> 10];
    int end = (b == NBk - 1) ? e : (base[ie] + sps[ie >> 10]);
    int m = end - beg;
    int qt = (n + 3) >> 2;
    int q1 = qt, q2 = 2 * qt, q3 = 3 * qt;
#pragma unroll
    for (int q = 0; q < 4; ++q) { cntq[t][q] = 0; curq[t][q] = 0; }
    __syncthreads();
    bool fits = (m <= SPART);
    if (fits) {   // stage + quartile-count in one global pass
        for (int j = t; j < m; j += 256) {
            int r = part[beg + j];
            spart[j] = r;
            int s = r & 0x00FFFFFF;
            int q = (s >= q1) + (s >= q2) + (s >= q3);
            atomicAdd(&cntq[((unsigned)r) >> 24][q], 1);
        }
    } else {      // fallback: count from global
        for (int j = t; j < m; j += 256) {
            int r = part[beg + j];
            int s = r & 0x00FFFFFF;
            int q = (s >= q1) + (s >= q2) + (s >= q3);
            atomicAdd(&cntq[((unsigned)r) >> 24][q], 1);
        }
    }
    __syncthreads();
    int c0 = cntq[t][0], c1 = cntq[t][1], c2 = cntq[t][2], c3 = cntq[t][3];
    int v = c0 + c1 + c2 + c3;
    int lane = t & 63, wid = t >> 6;
    int x = wave_incl_scan(v, lane);
    if (lane == 63) wsc[wid] = x;
    // rewrite cntq as row-internal exclusive quartile prefix
    cntq[t][0] = 0; cntq[t][1] = c0; cntq[t][2] = c0 + c1; cntq[t][3] = c0 + c1 + c2;
    __syncthreads();
    int woff = 0;
#pragma unroll
    for (int w = 0; w < 4; ++w) woff += (w < wid) ? wsc[w] : 0;
    int pre = x + woff - v;      // exclusive prefix within bucket
    spre[t] = pre;
    int node = b * 256 + t;
    if (node < n) {
        row_start[node] = beg + pre;
        dinv[node] = rsqrtf((float)v + 1.0f);  // +1 self-loop
    }
    if (b == NBk - 1 && t == 0) row_start[n] = e;
    __syncthreads();
    if (fits) {   // fill from LDS, quartile-ordered within each row
        for (int j = t; j < m; j += 256) {
            int r = spart[j];
            int dl = ((unsigned)r) >> 24;
            int s = r & 0x00FFFFFF;
            int q = (s >= q1) + (s >= q2) + (s >= q3);
            int off = atomicAdd(&curq[dl][q], 1);
            col[beg + spre[dl] + cntq[dl][q] + off] = s;
        }
    } else {      // fallback: fill from global
        for (int j = t; j < m; j += 256) {
            int r = part[beg + j];
            int dl = ((unsigned)r) >> 24;
            int s = r & 0x00FFFFFF;
            int q = (s >= q1) + (s >= q2) + (s >= q3);
            int off = atomicAdd(&curq[dl][q], 1);
            col[beg + spre[dl] + cntq[dl][q] + off] = s;
        }
    }
}

// ---- layer 1 GEMM: h1s(bf16) = (x @ W1) * dinv ; 32 nodes/block ----
__global__ void k_gemm1(const float* __restrict__ x, const float* __restrict__ W1,
                        const float* __restrict__ dinv,
                        __hip_bfloat162* __restrict__ h1s2, int n) {
    __shared__ float sW[FEAT_IN * FEAT_H];   // 8 KB
    __shared__ float sx[16][FEAT_IN + 1];
    int t = threadIdx.x;
    for (int i = t; i < FEAT_IN * FEAT_H; i += 256) sW[i] = W1[i];
#pragma unroll
    for (int tile = 0; tile < 2; ++tile) {
        int nodeBase = blockIdx.x * 32 + tile * 16;
        __syncthreads();
        {   // stage 16 nodes of x
            int xn = t >> 4, c = t & 15;
            int node = nodeBase + xn;
            if (node < n) {
                float4 v = ((const float4*)x)[(size_t)node * 16 + c];
                sx[xn][c * 4 + 0] = v.x; sx[xn][c * 4 + 1] = v.y;
                sx[xn][c * 4 + 2] = v.z; sx[xn][c * 4 + 3] = v.w;
            }
        }
        __syncthreads();
        int nl = t >> 4, g = t & 15;
        int node = nodeBase + nl;
        if (node < n) {
            float a0 = 0.0f, a1 = 0.0f;
#pragma unroll
            for (int k = 0; k < FEAT_IN; ++k) {
                float s = sx[nl][k];
                a0 += s * sW[k * FEAT_H + 2 * g];
                a1 += s * sW[k * FEAT_H + 2 * g + 1];
            }
            float dv = dinv[node];
            __hip_bfloat162 o;
            o.x = __float2bfloat16(a0 * dv);
            o.y = __float2bfloat16(a1 * dv);
            h1s2[(size_t)node * 16 + g] = o;
        }
    }
}

#define ACC8(u) do { float2 p_;                         \
    p_ = upk_bf2((u).x); a[0] += p_.x; a[1] += p_.y;    \
    p_ = upk_bf2((u).y); a[2] += p_.x; a[3] += p_.y;    \
    p_ = upk_bf2((u).z); a[4] += p_.x; a[5] += p_.y;    \
    p_ = upk_bf2((u).w); a[6] += p_.x; a[7] += p_.y; } while (0)

// ---- gather layer1 (+relu+bias) fused with GEMM2: 64 nodes x 4 lanes ----
__global__ void k_gather1_gemm2(const int* __restrict__ row_start, const int* __restrict__ col,
                                const uint4* __restrict__ h1q, const float* __restrict__ W2,
                                const float* __restrict__ b1,
                                const float* __restrict__ dinv,
                                __hip_bfloat162* __restrict__ h2s2, int n) {
    __shared__ float sW[FEAT_H * FEAT_O];
    __shared__ float sb1[FEAT_H];
    __shared__ float sz[64][FEAT_H + 1];
    int t = threadIdx.x;
    for (int i = t; i < FEAT_H * FEAT_O; i += 256) sW[i] = W2[i];
    if (t < FEAT_H) sb1[t] = b1[t];
    __syncthreads();

    int g = t >> 2, l = t & 3;          // 64 nodes, 4 lanes each (16B bf16 = 8 feats)
    int d = blockIdx.x * 64 + g;
    if (d < n) {
        float a[8];
        {   // self-loop term
            uint4 u = h1q[(size_t)d * 4 + l];
            float2 p;
            p = upk_bf2(u.x); a[0] = p.x; a[1] = p.y;
            p = upk_bf2(u.y); a[2] = p.x; a[3] = p.y;
            p = upk_bf2(u.z); a[4] = p.x; a[5] = p.y;
            p = upk_bf2(u.w); a[6] = p.x; a[7] = p.y;
        }
        int beg = row_start[d], end = row_start[d + 1];
        int j = beg;
        for (; j + 8 <= end; j += 8) {   // 8 independent 16B gathers in flight
            int c0 = col[j + 0], c1 = col[j + 1], c2 = col[j + 2], c3 = col[j + 3];
            int c4 = col[j + 4], c5 = col[j + 5], c6 = col[j + 6], c7 = col[j + 7];
            uint4 u0 = h1q[(size_t)c0 * 4 + l];
            uint4 u1 = h1q[(size_t)c1 * 4 + l];
            uint4 u2 = h1q[(size_t)c2 * 4 + l];
            uint4 u3 = h1q[(size_t)c3 * 4 + l];
            uint4 u4 = h1q[(size_t)c4 * 4 + l];
            uint4 u5 = h1q[(size_t)c5 * 4 + l];
            uint4 u6 = h1q[(size_t)c6 * 4 + l];
            uint4 u7 = h1q[(size_t)c7 * 4 + l];
            ACC8(u0); ACC8(u1); ACC8(u2); ACC8(u3);
            ACC8(u4); ACC8(u5); ACC8(u6); ACC8(u7);
        }
        for (; j + 4 <= end; j += 4) {
            int c0 = col[j + 0], c1 = col[j + 1], c2 = col[j + 2], c3 = col[j + 3];
            uint4 u0 = h1q[(size_t)c0 * 4 + l];
            uint4 u1 = h1q[(size_t)c1 * 4 + l];
            uint4 u2 = h1q[(size_t)c2 * 4 + l];
            uint4 u3 = h1q[(size_t)c3 * 4 + l];
            ACC8(u0); ACC8(u1); ACC8(u2); ACC8(u3);
        }
        for (; j < end; ++j) {
            uint4 u = h1q[(size_t)col[j] * 4 + l];
            ACC8(u);
        }
        float dv = dinv[d];
#pragma unroll
        for (int k = 0; k < 8; ++k)
            sz[g][l * 8 + k] = fmaxf(dv * a[k] + sb1[l * 8 + k], 0.0f);
    }
    __syncthreads();
    // GEMM2: 64 nodes x 8 output-pairs = 512 items / 256 thr = 2 iters; bf16 store
#pragma unroll
    for (int it = 0; it < 2; ++it) {
        int nl = (t >> 3) + it * 32;
        int m = t & 7;
        int node = blockIdx.x * 64 + nl;
        if (node < n) {
            float a0 = 0.0f, a1 = 0.0f;
#pragma unroll
            for (int f = 0; f < FEAT_H; ++f) {
                float z = sz[nl][f];
                a0 += z * sW[f * FEAT_O + 2 * m];
                a1 += z * sW[f * FEAT_O + 2 * m + 1];
            }
            float dv = dinv[node];
            __hip_bfloat162 o;
            o.x = __float2bfloat16(a0 * dv);
            o.y = __float2bfloat16(a1 * dv);
            h2s2[(size_t)node * 8 + m] = o;
        }
    }
}

// ---- gather layer2 + bias + log_softmax: 128 nodes x 2 lanes ----
__global__ void k_gather2_lsm(const int* __restrict__ row_start, const int* __restrict__ col,
                              const uint4* __restrict__ h2q, const float* __restrict__ b2,
                              const float* __restrict__ dinv,
                              float4* __restrict__ out4, int n) {
    __shared__ float sb2[FEAT_O];
    int t = threadIdx.x;
    if (t < FEAT_O) sb2[t] = b2[t];
    __syncthreads();
    int g = t >> 1, h = t & 1;          // 128 nodes, 2 lanes each (16B bf16 = 8 feats)
    int d = blockIdx.x * 128 + g;
    if (d >= n) return;
    float a[8];
    {
        uint4 u = h2q[(size_t)d * 2 + h];  // self-loop term
        float2 p;
        p = upk_bf2(u.x); a[0] = p.x; a[1] = p.y;
        p = upk_bf2(u.y); a[2] = p.x; a[3] = p.y;
        p = upk_bf2(u.z); a[4] = p.x; a[5] = p.y;
        p = upk_bf2(u.w); a[6] = p.x; a[7] = p.y;
    }
    int beg = row_start[d], end = row_start[d + 1];
    int j = beg;
    for (; j + 8 <= end; j += 8) {   // 8 independent 16B gathers in flight
        int c0 = col[j + 0], c1 = col[j + 1], c2 = col[j + 2], c3 = col[j + 3];
        int c4 = col[j + 4], c5 = col[j + 5], c6 = col[j + 6], c7 = col[j + 7];
        uint4 u0 = h2q[(size_t)c0 * 2 + h];
        uint4 u1 = h2q[(size_t)c1 * 2 + h];
        uint4 u2 = h2q[(size_t)c2 * 2 + h];
        uint4 u3 = h2q[(size_t)c3 * 2 + h];
        uint4 u4 = h2q[(size_t)c4 * 2 + h];
        uint4 u5 = h2q[(size_t)c5 * 2 + h];
        uint4 u6 = h2q[(size_t)c6 * 2 + h];
        uint4 u7 = h2q[(size_t)c7 * 2 + h];
        ACC8(u0); ACC8(u1); ACC8(u2); ACC8(u3);
        ACC8(u4); ACC8(u5); ACC8(u6); ACC8(u7);
    }
    for (; j + 4 <= end; j += 4) {
        int c0 = col[j + 0], c1 = col[j + 1], c2 = col[j + 2], c3 = col[j + 3];
        uint4 u0 = h2q[(size_t)c0 * 2 + h];
        uint4 u1 = h2q[(size_t)c1 * 2 + h];
        uint4 u2 = h2q[(size_t)c2 * 2 + h];
        uint4 u3 = h2q[(size_t)c3 * 2 + h];
        ACC8(u0); ACC8(u1); ACC8(u2); ACC8(u3);
    }
    for (; j < end; ++j) {
        uint4 u = h2q[(size_t)col[j] * 2 + h];
        ACC8(u);
    }
    float dv = dinv[d];
    float v[8];
    float mx = -1e30f;
#pragma unroll
    for (int k = 0; k < 8; ++k) {
        v[k] = dv * a[k] + sb2[h * 8 + k];
        mx = fmaxf(mx, v[k]);
    }
    mx = fmaxf(mx, __shfl_xor(mx, 1));   // partner lane = same node, other half
    float ssum = 0.0f;
#pragma unroll
    for (int k = 0; k < 8; ++k) ssum += __expf(v[k] - mx);
    ssum += __shfl_xor(ssum, 1);
    float lg = mx + logf(ssum);
    float4 o0 = { v[0] - lg, v[1] - lg, v[2] - lg, v[3] - lg };
    float4 o1 = { v[4] - lg, v[5] - lg, v[6] - lg, v[7] - lg };
    out4[(size_t)d * 4 + h * 2 + 0] = o0;
    out4[(size_t)d * 4 + h * 2 + 1] = o1;
}

extern "C" void kernel_launch(void* const* d_in, const int* in_sizes, int n_in,
                              void* d_out, int out_size, void* d_ws, size_t ws_size,
                              hipStream_t stream) {
    const float* x  = (const float*)d_in[0];
    const int*   ei = (const int*)d_in[1];
    const float* W1 = (const float*)d_in[2];
    const float* b1 = (const float*)d_in[3];
    const float* W2 = (const float*)d_in[4];
    const float* b2 = (const float*)d_in[5];

    const int n = in_sizes[0] / FEAT_IN;   // 100000
    const int e = in_sizes[1] / 2;         // 1600000
    const int* src = ei;
    const int* dst = ei + e;
    const int NBk = (n + 255) >> 8;        // 391 buckets of 256
    const int G = PART_G;                  // 512
    const int hlen = NBk * G;              // 200192
    const int snb = (hlen + 1023) / 1024;  // 196 (<= MAXSNB)

    // workspace; part (4B*e = 6.4MB) aliased with h1s bf16 (32n*2B = 6.4MB):
    // bucket_csr fully consumes part before k_gemm1 writes h1s (stream-ordered)
    int* part = (int*)d_ws;                                   // e ints
    __hip_bfloat162* h1s2 = (__hip_bfloat162*)d_ws;           // 16n bf162, same region
    int* col  = (int*)d_ws + e;                               // e ints
    __hip_bfloat162* h2s2 = (__hip_bfloat162*)(col + e);      // 8n bf162 (3.2MB)
    float* dinv = (float*)(h2s2 + 8 * (size_t)n);             // n
    int* hist      = (int*)(dinv + n);                        // hlen
    int* base      = hist + hlen;                             // hlen
    int* bsum      = base + hlen;                             // snb (raw block sums)
    int* row_start = bsum + MAXSNB;                           // n+1

    k_hist<<<G, 256, 0, stream>>>(dst, e, hist, G, NBk);
    k_scan1<<<snb, 256, 0, stream>>>(hist, base, bsum, hlen);
    k_partition<<<G, 256, 0, stream>>>(src, dst, e, base, bsum, snb, part, G, NBk);
    k_bucket_csr<<<NBk, 256, 0, stream>>>(part, base, bsum, snb, e, G, NBk, n,
                                          row_start, col, dinv);

    k_gemm1<<<(n + 31) / 32, 256, 0, stream>>>(x, W1, dinv, h1s2, n);
    k_gather1_gemm2<<<(n + 63) / 64, 256, 0, stream>>>(row_start, col, (const uint4*)h1s2,
                                                       W2, b1, dinv, h2s2, n);
    k_gather2_lsm<<<(n + 127) / 128, 256, 0, stream>>>(row_start, col, (const uint4*)h2s2,
                                                       b2, dinv, (float4*)d_out, n);
}